// Round 11
// baseline (191.967 us; speedup 1.0000x reference)
//
#include <hip/hip_runtime.h>

typedef __attribute__((ext_vector_type(4))) int i32x4;

// ---------------------------------------------------------------------------
// Helpers
// ---------------------------------------------------------------------------
__device__ __forceinline__ void gload_lds16(const void* g, void* l) {
  // async global->LDS, 16B/lane. LDS dest must be wave-uniform base + lane*16.
  __builtin_amdgcn_global_load_lds((const __attribute__((address_space(1))) void*)g,
                                   (__attribute__((address_space(3))) void*)l,
                                   16, 0, 0);
}

#define BARRIER() __builtin_amdgcn_s_barrier()
#define LGKM0()   asm volatile("s_waitcnt lgkmcnt(0)" ::: "memory")
#define VMCNT4()  asm volatile("s_waitcnt vmcnt(4)" ::: "memory")

// ---------------------------------------------------------------------------
// Fused quantize f32 -> int8 for both x and w (round-half-even, clamp +-127)
// ---------------------------------------------------------------------------
__global__ void quant_both_kernel(const float* __restrict__ x,
                                  const float* __restrict__ w,
                                  signed char* __restrict__ qx,
                                  signed char* __restrict__ qw,
                                  const float* __restrict__ amax_x,
                                  const float* __restrict__ amax_w,
                                  int nx4, int nw4) {
  const float sx = 127.0f / amax_x[0];
  const float sw = 127.0f / amax_w[0];
  int i = blockIdx.x * blockDim.x + threadIdx.x;
  const int stride = gridDim.x * blockDim.x;
  const int ntot = nx4 + nw4;
  for (; i < ntot; i += stride) {
    const bool isx = i < nx4;
    const float4* src = isx ? (const float4*)x : (const float4*)w;
    int* dst = isx ? (int*)qx : (int*)qw;
    const int j = isx ? i : i - nx4;
    const float s = isx ? sx : sw;
    float4 v = src[j];
    int q0 = (int)rintf(fminf(fmaxf(v.x * s, -127.0f), 127.0f));
    int q1 = (int)rintf(fminf(fmaxf(v.y * s, -127.0f), 127.0f));
    int q2 = (int)rintf(fminf(fmaxf(v.z * s, -127.0f), 127.0f));
    int q3 = (int)rintf(fminf(fmaxf(v.w * s, -127.0f), 127.0f));
    dst[j] = (q0 & 255) | ((q1 & 255) << 8) | ((q2 & 255) << 16) | ((q3 & 255) << 24);
  }
}

// ---------------------------------------------------------------------------
// 256x256 8-phase int8 GEMM — R3 skeleton with (m-half, k-sub) phase split.
// Read distribution 8/8/4/4 per K-tile (was 12/4/8/0): worst-case CU-wide
// ds_read drain 768 cyc vs 653 cyc MFMA cover (was 1150), so the LDS pipe
// overlaps MFMA every phase instead of serializing in front of P1/P5.
// Staging plan, vmcnt(4) gates, swizzle, epilogue: verbatim round-3
// (buffer liveness windows unchanged: B0 last read P2, A0 P4, B1 P6, A1 P8).
// out[N,M] = dequant(qx[N,K] . qw[M,K]^T) + bias
// 512 thr = 8 waves (2M x 4N), per-wave 128x64, mfma_i32_16x16x64_i8,
// BK=128 int8 (2 k-subtiles of 64), LDS 2dbuf x (A,B) x [256][128B] = 128 KiB.
// ---------------------------------------------------------------------------
__global__ __launch_bounds__(512, 2) void gemm_i8_8p(
    const signed char* __restrict__ qx,   // [N,K]
    const signed char* __restrict__ qw,   // [M,K]
    const float* __restrict__ bias,       // [M]
    const float* __restrict__ amax_x,
    const float* __restrict__ amax_w,
    float* __restrict__ out,              // [N,M]
    int N, int M, int K) {
  constexpr int BKB = 128;  // K bytes per tile

  __shared__ signed char lds[4][256 * 128];  // [A0,B0,A1,B1], 32 KiB each

  const int tid  = threadIdx.x;
  const int lane = tid & 63;
  const int wid  = tid >> 6;
  const int wm   = wid >> 2;   // 0..1
  const int wn   = wid & 3;    // 0..3
  const int l15  = lane & 15;
  const int l4   = lane >> 4;

  // bijective XCD-aware block swizzle (nwg = 512, divisible by 8)
  const int nbn = M >> 8;                      // 16
  const int nwg = (N >> 8) * nbn;              // 512
  const int cpx = nwg >> 3;
  const int swz = (blockIdx.x & 7) * cpx + (blockIdx.x >> 3);
  const int rowBase = (swz / nbn) << 8;
  const int colBase = (swz % nbn) << 8;

  // staging source pointers: thread t covers slots {h*1024 + L*512 + t};
  // logical (row = slot>>3, c = (slot&7) ^ (row&7)); LDS dest stays linear.
  const signed char* sA[2][2];
  const signed char* sB[2][2];
#pragma unroll
  for (int h = 0; h < 2; ++h)
#pragma unroll
    for (int L = 0; L < 2; ++L) {
      const int slot = h * 1024 + L * 512 + tid;
      const int row  = slot >> 3;
      const int c    = (slot & 7) ^ (row & 7);
      sA[h][L] = qx + (size_t)(rowBase + row) * K + c * 16;
      sB[h][L] = qw + (size_t)(colBase + row) * K + c * 16;
    }

  signed char* A0 = lds[0];
  signed char* B0 = lds[1];
  signed char* A1 = lds[2];
  signed char* B1 = lds[3];

#define STAGE(dst, src, h, kt)                                             \
  do {                                                                     \
    gload_lds16(src[h][0] + (kt) * BKB, (dst) + (h)*16384 + tid * 16);     \
    gload_lds16(src[h][1] + (kt) * BKB, (dst) + (h)*16384 + 8192 + tid * 16); \
  } while (0)

  // fragment-read addressing (row&7 == l15&7 since frag bases are mult of 16)
  const int ck0 = ((l4) ^ (l15 & 7)) * 16;       // ks=0 chunk offset
  const int ck1 = ((4 + l4) ^ (l15 & 7)) * 16;   // ks=1
  const int aRow0 = (wm * 128 + l15) * 128;
  const int bRow0 = (wn * 64 + l15) * 128;

  i32x4 acc[8][4] = {{{0}}};
  i32x4 af0[4], af1[4];   // A m-half sets (overwritten each phase, WAR-safe)
  i32x4 bf[4][2];         // B all-nj, both k-subs (ks1 pre-read one phase early)

  // read A m-half (mh) for k-sub ks into AF (4 reads)
#define RDAH(AF, R, mh, ks)                                                 \
  {                                                                         \
    _Pragma("unroll") for (int q = 0; q < 4; ++q)                           \
        AF[q] = *(const i32x4*)((R) + aRow0 + ((mh)*4 + q) * 2048 +         \
                                ((ks) ? ck1 : ck0));                        \
  }
  // read B all nj for k-sub ks (4 reads)
#define RDBALL(R, ks)                                                       \
  {                                                                         \
    _Pragma("unroll") for (int nj = 0; nj < 4; ++nj)                        \
        bf[nj][ks] = *(const i32x4*)((R) + bRow0 + nj * 2048 +              \
                                     ((ks) ? ck1 : ck0));                   \
  }
  // 16 MFMA: acc[mb..mb+3][all nj] += AF x bf[.][ks]
#define MFMAH(mb, AF, ks)                                                   \
  {                                                                         \
    __builtin_amdgcn_s_setprio(1);                                          \
    _Pragma("unroll") for (int mi = 0; mi < 4; ++mi)                        \
        _Pragma("unroll") for (int nj = 0; nj < 4; ++nj)                    \
            acc[(mb) + mi][nj] = __builtin_amdgcn_mfma_i32_16x16x64_i8(     \
                AF[mi], bf[nj][ks], acc[(mb) + mi][nj], 0, 0, 0);           \
    __builtin_amdgcn_s_setprio(0);                                          \
  }

  const int T = K / BKB;  // 32 K-tiles

  // prologue: tile0 -> A0/B0 (8 loads), tile1's B -> B1 (4 loads).
  // vmcnt(4): every wave's A0/B0 loads complete; B1 floats. Barrier publishes.
  STAGE(B0, sB, 0, 0); STAGE(B0, sB, 1, 0);
  STAGE(A0, sA, 0, 0); STAGE(A0, sA, 1, 0);
  STAGE(B1, sB, 0, 1); STAGE(B1, sB, 1, 1);
  VMCNT4();
  BARRIER();

  for (int it = 0; it < T / 2; ++it) {
    const int k1 = 2 * it + 1;
    const int k2 = (2 * it + 2 < T) ? 2 * it + 2 : T - 1;  // clamped (stale, never read)
    const int k3 = (2 * it + 3 < T) ? 2 * it + 3 : T - 1;

    // ---- tile t (A0/B0) ----
    // P1: read af(m0,ks0)+bf(all,ks0) [8]; stage A1h0 <- t+1
    RDAH(af0, A0, 0, 0); RDBALL(B0, 0);
    STAGE(A1, sA, 0, k1);
    BARRIER(); LGKM0();
    MFMAH(0, af0, 0);
    BARRIER();

    // P2: read af(m1,ks0) + PRE-READ bf(all,ks1) [8]; stage A1h1 <- t+1.
    //     B0's last read is here -> B0 free from P3 (same liveness as R3).
    RDAH(af1, A0, 1, 0); RDBALL(B0, 1);
    STAGE(A1, sA, 1, k1);
    BARRIER(); LGKM0();
    MFMAH(4, af1, 0);
    BARRIER();

    // P3: read af(m0,ks1) [4]; stage B0h0 <- t+2
    RDAH(af0, A0, 0, 1);
    STAGE(B0, sB, 0, k2);
    BARRIER(); LGKM0();
    MFMAH(0, af0, 1);
    BARRIER();

    // P4: read af(m1,ks1) [4]; stage B0h1 <- t+2. A0's last read is here.
    //     GATE tile t+1 (A1 from P1/P2, B1 from prev P7/P8): vmcnt(4)
    //     leaves only P3/P4's B0 loads in flight; barrier publishes.
    RDAH(af1, A0, 1, 1);
    STAGE(B0, sB, 1, k2);
    BARRIER(); LGKM0();
    MFMAH(4, af1, 1);
    VMCNT4();
    BARRIER();

    // ---- tile t+1 (A1/B1), mirror ----
    // P5: read af(m0,ks0)+bf(all,ks0) [8]; stage A0h0 <- t+2
    RDAH(af0, A1, 0, 0); RDBALL(B1, 0);
    STAGE(A0, sA, 0, k2);
    BARRIER(); LGKM0();
    MFMAH(0, af0, 0);
    BARRIER();

    // P6: read af(m1,ks0) + pre-read bf(all,ks1) [8]; stage A0h1 <- t+2.
    //     B1's last read is here -> B1 free from P7.
    RDAH(af1, A1, 1, 0); RDBALL(B1, 1);
    STAGE(A0, sA, 1, k2);
    BARRIER(); LGKM0();
    MFMAH(4, af1, 0);
    BARRIER();

    // P7: read af(m0,ks1) [4]; stage B1h0 <- t+3
    RDAH(af0, A1, 0, 1);
    STAGE(B1, sB, 0, k3);
    BARRIER(); LGKM0();
    MFMAH(0, af0, 1);
    BARRIER();

    // P8: read af(m1,ks1) [4]; stage B1h1 <- t+3. A1's last read is here.
    //     GATE tile t+2's A0/B0 (P3-P6 loads): vmcnt(4) leaves only
    //     P7/P8's B1 loads in flight; barrier publishes.
    RDAH(af1, A1, 1, 1);
    STAGE(B1, sB, 1, k3);
    BARRIER(); LGKM0();
    MFMAH(4, af1, 1);
    VMCNT4();
    BARRIER();
  }

  // epilogue: dequant + bias. C/D: col = lane&15, row = (lane>>4)*4 + reg
  const float dq = amax_x[0] * amax_w[0] * (1.0f / (127.0f * 127.0f));
#pragma unroll
  for (int nj = 0; nj < 4; ++nj) {
    const int col = colBase + wn * 64 + nj * 16 + l15;
    const float bv = bias[col];
#pragma unroll
    for (int mi = 0; mi < 8; ++mi) {
      const int row = rowBase + wm * 128 + mi * 16 + l4 * 4;
#pragma unroll
      for (int r = 0; r < 4; ++r)
        out[(size_t)(row + r) * M + col] = (float)acc[mi][nj][r] * dq + bv;
    }
  }
#undef STAGE
#undef RDAH
#undef RDBALL
#undef MFMAH
}

// ---------------------------------------------------------------------------
// Launch
// ---------------------------------------------------------------------------
extern "C" void kernel_launch(void* const* d_in, const int* in_sizes, int n_in,
                              void* d_out, int out_size, void* d_ws, size_t ws_size,
                              hipStream_t stream) {
  const float* x      = (const float*)d_in[0];
  const float* w      = (const float*)d_in[1];
  const float* bias   = (const float*)d_in[2];
  const float* amax_x = (const float*)d_in[3];
  const float* amax_w = (const float*)d_in[4];
  float* out = (float*)d_out;

  const int M = in_sizes[2];                    // 4096
  const int K = in_sizes[1] / M;                // 4096
  const int N = (int)((long)in_sizes[0] / K);   // 8192

  signed char* qx = (signed char*)d_ws;         // [N,K] int8
  signed char* qw = qx + (size_t)N * K;         // [M,K] int8

  const int nx4 = N * (K / 4);
  const int nw4 = M * (K / 4);
  quant_both_kernel<<<2048, 256, 0, stream>>>(x, w, qx, qw, amax_x, amax_w,
                                              nx4, nw4);

  const int nwg = (N / 256) * (M / 256);        // 512
  gemm_i8_8p<<<nwg, 512, 0, stream>>>(qx, qw, bias, amax_x, amax_w, out,
                                      N, M, K);
}